// Round 8
// baseline (587.487 us; speedup 1.0000x reference)
//
#include <hip/hip_runtime.h>
#include <hip/hip_bf16.h>
#include <math.h>

#define DEV_INLINE __device__ __forceinline__

typedef __attribute__((ext_vector_type(8))) short short8;
typedef __attribute__((ext_vector_type(8))) unsigned short ushort8v;
typedef __attribute__((ext_vector_type(4))) float f32x4;

constexpr int H = 128, W = 128, C = 128, B = 4;
constexpr int HWc = H * W;        // 16384
constexpr int KK = 9;
constexpr int KT2 = 1184;         // 37 chunks * 32

DEV_INLINE unsigned short f2bf(float f) {
  union { float f; unsigned u; } v; v.f = f;
  unsigned r = v.u + 0x7FFFu + ((v.u >> 16) & 1u);   // RNE
  return (unsigned short)(r >> 16);
}
DEV_INLINE float ubits(unsigned u) {
  union { unsigned u; float f; } v; v.u = u; return v.f;
}
DEV_INLINE float bfu(unsigned short u) { return ubits(((unsigned)u) << 16); }
DEV_INLINE unsigned pack2bf(float a, float b) {
  float2 t; t.x = a; t.y = b;
  __hip_bfloat162 h = __float22bfloat162_rn(t);
  union { __hip_bfloat162 h; unsigned u; } c; c.h = h;
  return c.u;
}

// Fused implicit GEMM over NHWC bf16, K-split x2. Block = 128 thr (2 waves)
// on 32 positions; wave wv owns channel-groups {2wv, 2wv+1} (18 chunks);
// wave 0 also does the BN-shift chunk (layer 1). Chunk ch = tap*4 + cg;
// k = q*8+j -> channel cg*32+q*8+j at tap. A-frags from swizzled global
// table wS[ch][NT][64][8] (L1-hot). Gathers: 4 corners x 16 B contiguous
// (NHWC). fp32 partials reduced via LDS overlaying the bilinear table
// (barrier-separated). Grid 2048 x 128 -> 16 waves/CU.
// MODE 0: plain conv O=32 -> fp32 offsets+mask. MODE 1: deform O=128,
// PReLU -> NHWC bf16. MODE 2: deform O=128, BN2 + NCHW residual -> fp32.
template<int MODE, bool BN>
__global__ __launch_bounds__(128, 4)
void gemm8(const unsigned short* __restrict__ src,     // NHWC bf16 (B,H,W,C)
           const unsigned short* __restrict__ wS,      // [37][NT][64][8]
           const float* __restrict__ offs,             // (B,18,H,W) fp32
           const float* __restrict__ msk,              // (B,9,H,W) fp32
           const float* __restrict__ pA, const float* __restrict__ pB,
           const float* __restrict__ pM, const float* __restrict__ pV,
           const float* __restrict__ resid,
           float* __restrict__ outf,                   // MODE0 offs / MODE2 out
           unsigned short* __restrict__ outh,          // MODE1 NHWC bf16
           float* __restrict__ out1)                   // MODE0 mask
{
  constexpr int NT = (MODE == 0) ? 2 : 8;
  constexpr size_t TBLSZ = (MODE != 0) ? (size_t)KK * 32 * 20 : 16;  // sId+sWt
  constexpr size_t REDSZ = (size_t)2 * NT * 4 * 64 * 4;              // fp32
  constexpr size_t SMSZ  = TBLSZ > REDSZ ? TBLSZ : REDSZ;
  __shared__ __attribute__((aligned(16))) char smem[SMSZ];
  ushort2* sId = (ushort2*)smem;                       // [288]
  float4*  sWt = (float4*)(smem + KK * 32 * 4);        // [288]
  float*   red = (float*)smem;                         // overlays table

  const int tid  = threadIdx.x;
  const int lane = tid & 63;
  const int m16  = lane & 15;
  const int q    = lane >> 4;
  const int wv   = tid >> 6;

  const int raw  = blockIdx.x;                // 2048 blocks
  const int xcd  = raw & 7;
  const int slot = raw >> 3;                  // [0,256)
  const int b    = xcd >> 1;
  const int hy   = ((xcd & 1) << 6) | (slot >> 2);
  const int hx0  = (slot & 3) << 5;           // 32-wide segment
  const unsigned short* __restrict__ srcB = src + ((size_t)b << 14) * C;

  // ---- bilinear table: 9 taps x 32 positions (both waves build) ----
  if constexpr (MODE != 0) {
    for (int e = tid; e < KK * 32; e += 128) {
      const int tap = e >> 5;
      const int hx  = hx0 + (e & 31);
      const int ky  = tap / 3, kx = tap - 3 * (tap / 3);
      const size_t ob = ((size_t)(b * 18 + 2 * tap) * H + hy) * W + hx;
      const float oy = offs[ob];
      const float ox = offs[ob + (size_t)HWc];
      const float mv = msk[((size_t)(b * 9 + tap) * H + hy) * W + hx];
      const float py = (float)(hy - 1 + ky) + oy;
      const float px = (float)(hx - 1 + kx) + ox;
      const float fy = floorf(py), fx = floorf(px);
      const float ay = py - fy, ax = px - fx;
      const int y0 = (int)fy, x0 = (int)fx;
      const int y1 = y0 + 1, x1 = x0 + 1;
      const float wyt = (1.f - ay) * (((unsigned)y0 < (unsigned)H) ? 1.f : 0.f);
      const float wyb = ay * (((unsigned)y1 < (unsigned)H) ? 1.f : 0.f);
      const int y0c = min(max(y0, 0), H - 1), y1c = min(max(y1, 0), H - 1);
      const int bx  = min(max(x0, 0), W - 2);
      float wA = 0.f, wB = 0.f;
      if (x0 == bx)          { wA = 1.f - ax; wB = ax; }
      else if (x1 == bx)     { wA = ax; }
      else if (x0 == bx + 1) { wB = 1.f - ax; }
      sId[e] = make_ushort2((unsigned short)(y0c * W + bx),
                            (unsigned short)(y1c * W + bx));
      sWt[e] = make_float4(mv * wyt * wA, mv * wyt * wB,
                           mv * wyb * wA, mv * wyb * wB);
    }
    __syncthreads();
  }

  f32x4 acc[2][NT];
  #pragma unroll
  for (int g = 0; g < 2; ++g)
    #pragma unroll
    for (int i = 0; i < NT; ++i) acc[g][i] = (f32x4){0.f, 0.f, 0.f, 0.f};

  const int choff = q << 3;

  for (int tap = 0; tap < 9; ++tap) {
    // per-group table entry (shared by both cg chunks of this tap)
    ushort2 id[2]; float4 wt[2];
    if constexpr (MODE != 0) {
      #pragma unroll
      for (int g = 0; g < 2; ++g) {
        const int e = (tap << 5) + (g << 4) + m16;
        id[g] = sId[e]; wt[g] = sWt[e];
      }
    }
    #pragma unroll
    for (int cgi = 0; cgi < 2; ++cgi) {
      const int cg = (wv << 1) + cgi;
      const int ch = (tap << 2) + cg;
      const int cbase = (cg << 5) + choff;
      const unsigned short* ap = wS + ((size_t)ch * NT * 64 + lane) * 8;
      short8 afr[NT];
      #pragma unroll
      for (int ot = 0; ot < NT; ++ot)
        afr[ot] = *(const short8*)(ap + (size_t)ot * 512);

      #pragma unroll
      for (int g = 0; g < 2; ++g) {
        union { unsigned u[4]; short8 s; } bfr;
        if constexpr (MODE != 0) {
          const unsigned short* pT  = srcB + ((size_t)id[g].x * C + cbase);
          const unsigned short* pBt = srcB + ((size_t)id[g].y * C + cbase);
          const ushort8v TL = *(const ushort8v*)(pT);
          const ushort8v TR = *(const ushort8v*)(pT + C);
          const ushort8v BL = *(const ushort8v*)(pBt);
          const ushort8v BR = *(const ushort8v*)(pBt + C);
          float sv[8];
          #pragma unroll
          for (int j = 0; j < 8; ++j)
            sv[j] = wt[g].x * bfu(TL[j]) + wt[g].y * bfu(TR[j])
                  + wt[g].z * bfu(BL[j]) + wt[g].w * bfu(BR[j]);
          #pragma unroll
          for (int t = 0; t < 4; ++t) bfr.u[t] = pack2bf(sv[2 * t], sv[2 * t + 1]);
        } else {
          const int ky = tap / 3, kx = tap - 3 * (tap / 3);
          const int iy = hy + ky - 1;
          const int ix = hx0 + (g << 4) + m16 + kx - 1;
          const bool vok = ((unsigned)iy < (unsigned)H) && ((unsigned)ix < (unsigned)W);
          const int rb = vok ? (iy * W + ix) : 0;
          const ushort8v v = *(const ushort8v*)(srcB + ((size_t)rb * C + cbase));
          #pragma unroll
          for (int t = 0; t < 4; ++t) {
            const unsigned short lo = vok ? v[2 * t]     : (unsigned short)0;
            const unsigned short hi = vok ? v[2 * t + 1] : (unsigned short)0;
            bfr.u[t] = (unsigned)lo | ((unsigned)hi << 16);
          }
        }
        #pragma unroll
        for (int ot = 0; ot < NT; ++ot)
          acc[g][ot] = __builtin_amdgcn_mfma_f32_16x16x32_bf16(afr[ot], bfr.s, acc[g][ot], 0, 0, 0);
      }
    }
  }

  if constexpr (BN) {   // chunk 36 (BN-shift), wave 0 only
    if (wv == 0) {
      const unsigned short* ap = wS + ((size_t)36 * NT * 64 + lane) * 8;
      short8 afr[NT];
      #pragma unroll
      for (int ot = 0; ot < NT; ++ot)
        afr[ot] = *(const short8*)(ap + (size_t)ot * 512);
      #pragma unroll
      for (int g = 0; g < 2; ++g) {
        union { unsigned u[4]; short8 s; } bfr;
        float sv[8];
        #pragma unroll
        for (int j = 0; j < 8; ++j) {
          const int kj = (q << 3) + j;
          float s = 0.f;
          if (kj < KK) {
            if constexpr (MODE != 0) {
              const float4 wt = sWt[(kj << 5) + (g << 4) + m16];
              s = wt.x + wt.y + wt.z + wt.w;
            } else {
              const int ky = kj / 3, kx = kj - 3 * (kj / 3);
              const int iy = hy + ky - 1;
              const int ix = hx0 + (g << 4) + m16 + kx - 1;
              s = (((unsigned)iy < (unsigned)H) && ((unsigned)ix < (unsigned)W)) ? 1.f : 0.f;
            }
          }
          sv[j] = s;
        }
        #pragma unroll
        for (int t = 0; t < 4; ++t) bfr.u[t] = pack2bf(sv[2 * t], sv[2 * t + 1]);
        #pragma unroll
        for (int ot = 0; ot < NT; ++ot)
          acc[g][ot] = __builtin_amdgcn_mfma_f32_16x16x32_bf16(afr[ot], bfr.s, acc[g][ot], 0, 0, 0);
      }
    }
  }

  // ---- K-split reduction (red overlays the table; barriers separate) ----
  __syncthreads();
  if (wv == 1) {
    #pragma unroll
    for (int g = 0; g < 2; ++g)
      #pragma unroll
      for (int ot = 0; ot < NT; ++ot)
        #pragma unroll
        for (int rg = 0; rg < 4; ++rg)
          red[(((g * NT) + ot) * 4 + rg) * 64 + lane] = acc[g][ot][rg];
  }
  __syncthreads();
  if (wv != 0) return;

  // ---- epilogue (wave 0): D col = m16 -> position, row = q*4+rg -> o ----
  #pragma unroll
  for (int g = 0; g < 2; ++g) {
    const int hx = hx0 + (g << 4) + m16;
    #pragma unroll
    for (int ot = 0; ot < NT; ++ot) {
      float vv4[4];
      #pragma unroll
      for (int rg = 0; rg < 4; ++rg)
        vv4[rg] = acc[g][ot][rg] + red[(((g * NT) + ot) * 4 + rg) * 64 + lane];
      if constexpr (MODE == 1) {
        unsigned u0, u1;
        {
          const float a0 = pA[ot * 16 + (q << 2) + 0];
          const float a1 = pA[ot * 16 + (q << 2) + 1];
          const float a2 = pA[ot * 16 + (q << 2) + 2];
          const float a3 = pA[ot * 16 + (q << 2) + 3];
          u0 = pack2bf(vv4[0] > 0.f ? vv4[0] : a0 * vv4[0],
                       vv4[1] > 0.f ? vv4[1] : a1 * vv4[1]);
          u1 = pack2bf(vv4[2] > 0.f ? vv4[2] : a2 * vv4[2],
                       vv4[3] > 0.f ? vv4[3] : a3 * vv4[3]);
        }
        uint2 st; st.x = u0; st.y = u1;
        const int n = (b << 14) + hy * W + hx;
        *(uint2*)(outh + (size_t)n * C + ot * 16 + (q << 2)) = st;
      } else {
        #pragma unroll
        for (int rg = 0; rg < 4; ++rg) {
          const int o = ot * 16 + (q << 2) + rg;
          const float vv = vv4[rg];
          if constexpr (MODE == 0) {
            if (o < 18) {
              outf[((size_t)(b * 18 + o) * H + hy) * W + hx] = vv + pA[o];
            } else if (o < 27) {
              const float z = vv + pA[o];
              out1[((size_t)(b * 9 + (o - 18)) * H + hy) * W + hx] = 2.f / (1.f + expf(-z));
            }
          } else {
            const size_t oi = (((size_t)(b * C + o)) << 14) + hy * W + hx;
            const float s  = pA[o] * rsqrtf(pV[o] + 1e-5f);
            const float sh = pB[o] - pM[o] * s;
            outf[oi] = vv * s + sh + resid[oi];
          }
        }
      }
    }
  }
}

// NCHW fp32 -> NHWC bf16, LDS-tiled (coalesced loads AND stores)
__global__ __launch_bounds__(256, 4)
void xcvt3(const float* __restrict__ x, unsigned short* __restrict__ xb)
{
  __shared__ unsigned tile[64 * 69];          // [pos][ch-pair], stride 69
  const int b   = blockIdx.y;
  const int p0  = blockIdx.x * 64;
  const int tid = threadIdx.x;
  const int pl  = tid & 63;
  const int cg  = tid >> 6;                   // 0..3
  const float* __restrict__ xp = x + (((size_t)(b * C) + cg * 32) << 14) + p0 + pl;
  #pragma unroll
  for (int j = 0; j < 16; ++j) {
    const float a = xp[(size_t)(2 * j) << 14];
    const float c = xp[(size_t)(2 * j + 1) << 14];
    tile[pl * 69 + cg * 16 + j] = pack2bf(a, c);
  }
  __syncthreads();
  const int pl2 = tid >> 2;
  const int cq  = tid & 3;
  unsigned* dst = (unsigned*)(xb + (((size_t)(b << 14)) + p0 + pl2) * C + cq * 32);
  #pragma unroll
  for (int k = 0; k < 16; k += 4) {
    uint4 v;
    v.x = tile[pl2 * 69 + cq * 16 + k];
    v.y = tile[pl2 * 69 + cq * 16 + k + 1];
    v.z = tile[pl2 * 69 + cq * 16 + k + 2];
    v.w = tile[pl2 * 69 + cq * 16 + k + 3];
    *(uint4*)(dst + k) = v;
  }
}

// Swizzled weights, tap-major chunks: wS[((ch*NT+ot)*64+lane)*8+j] =
// w[o=ot*16+(lane&15)][c=(ch&3)*32+(lane>>4)*8+j][tap=ch>>2] (ch<36);
// ch==36: BN-shift col (kj=(lane>>4)*8+j < 9), layer-1 only.
__global__ void prep5(const float* __restrict__ w1, const float* __restrict__ w2,
                      const float* __restrict__ ow1, const float* __restrict__ mw1,
                      const float* __restrict__ ob1, const float* __restrict__ mb1,
                      const float* __restrict__ ow2, const float* __restrict__ mw2,
                      const float* __restrict__ ob2, const float* __restrict__ mb2,
                      const float* __restrict__ g, const float* __restrict__ bb,
                      const float* __restrict__ m, const float* __restrict__ v,
                      unsigned short* __restrict__ wb1, unsigned short* __restrict__ wb2,
                      unsigned short* __restrict__ wom1, unsigned short* __restrict__ wom2,
                      float* __restrict__ bias1, float* __restrict__ bias2)
{
  const int i = blockIdx.x * 256 + threadIdx.x;
  if (i < 128 * KT2) {              // deform, NT=8
    const int j = i & 7, lane = (i >> 3) & 63, ot = (i >> 9) & 7, ch = i >> 12;
    const int o = ot * 16 + (lane & 15);
    const int qj = ((lane >> 4) << 3) + j;
    unsigned short v1 = 0, v2 = 0;
    if (ch < 36) {
      const int tap = ch >> 2;
      const int c   = ((ch & 3) << 5) + qj;
      const float s = g[c] * rsqrtf(v[c] + 1e-5f);
      v1 = f2bf(w1[(size_t)(o * 128 + c) * 9 + tap] * s);
      v2 = f2bf(w2[(size_t)(o * 128 + c) * 9 + tap]);
    } else if (qj < KK) {
      float acc = 0.f;
      for (int c = 0; c < 128; ++c) {
        const float s  = g[c] * rsqrtf(v[c] + 1e-5f);
        const float sh = bb[c] - m[c] * s;
        acc += w1[(size_t)(o * 128 + c) * 9 + qj] * sh;
      }
      v1 = f2bf(acc);
    }
    wb1[i] = v1; wb2[i] = v2;
  }
  if (i < 32 * KT2) {               // offset/mask, NT=2
    const int j = i & 7, lane = (i >> 3) & 63, ot = (i >> 9) & 1, ch = i >> 10;
    const int o = ot * 16 + (lane & 15);
    const int qj = ((lane >> 4) << 3) + j;
    unsigned short v1 = 0, v2 = 0;
    if (ch < 36) {
      const int tap = ch >> 2;
      const int c   = ((ch & 3) << 5) + qj;
      const float s = g[c] * rsqrtf(v[c] + 1e-5f);
      if (o < 18) {
        v1 = f2bf(ow1[(size_t)(o * 128 + c) * 9 + tap] * s);
        v2 = f2bf(ow2[(size_t)(o * 128 + c) * 9 + tap]);
      } else if (o < 27) {
        v1 = f2bf(mw1[(size_t)((o - 18) * 128 + c) * 9 + tap] * s);
        v2 = f2bf(mw2[(size_t)((o - 18) * 128 + c) * 9 + tap]);
      }
    } else if (qj < KK && o < 27) {
      const float* wsrc = (o < 18) ? ow1 + (size_t)o * 1152
                                   : mw1 + (size_t)(o - 18) * 1152;
      float acc = 0.f;
      for (int c = 0; c < 128; ++c) {
        const float s  = g[c] * rsqrtf(v[c] + 1e-5f);
        const float sh = bb[c] - m[c] * s;
        acc += wsrc[(size_t)c * 9 + qj] * sh;
      }
      v1 = f2bf(acc);
    }
    wom1[i] = v1; wom2[i] = v2;
  }
  if (i < 32) {
    float b1 = 0.f, b2 = 0.f;
    if (i < 18)      { b1 = ob1[i];      b2 = ob2[i]; }
    else if (i < 27) { b1 = mb1[i - 18]; b2 = mb2[i - 18]; }
    bias1[i] = b1; bias2[i] = b2;
  }
}

extern "C" void kernel_launch(void* const* d_in, const int* in_sizes, int n_in,
                              void* d_out, int out_size, void* d_ws, size_t ws_size,
                              hipStream_t stream)
{
  const float* x     = (const float*)d_in[0];
  const float* bn1g  = (const float*)d_in[1];
  const float* bn1b  = (const float*)d_in[2];
  const float* bn1m  = (const float*)d_in[3];
  const float* bn1v  = (const float*)d_in[4];
  const float* ow1   = (const float*)d_in[5];
  const float* ob1   = (const float*)d_in[6];
  const float* mw1   = (const float*)d_in[7];
  const float* mb1   = (const float*)d_in[8];
  const float* w1    = (const float*)d_in[9];
  const float* alpha = (const float*)d_in[10];
  const float* ow2   = (const float*)d_in[11];
  const float* ob2   = (const float*)d_in[12];
  const float* mw2   = (const float*)d_in[13];
  const float* mb2   = (const float*)d_in[14];
  const float* w2    = (const float*)d_in[15];
  const float* bn2g  = (const float*)d_in[16];
  const float* bn2b  = (const float*)d_in[17];
  const float* bn2m  = (const float*)d_in[18];
  const float* bn2v  = (const float*)d_in[19];
  float* out = (float*)d_out;

  char* wsp = (char*)d_ws;
  unsigned short* xbf  = (unsigned short*)(wsp);             // NHWC bf16, 16777216
  unsigned short* r2bf = (unsigned short*)(wsp + 16777216);  // NHWC bf16, 16777216
  float* offb = (float*)(wsp + 33554432);                    // 4718592
  float* mskb = (float*)(wsp + 38273024);                    // 2359296
  unsigned short* wb1  = (unsigned short*)(wsp + 40632320);  // 303104
  unsigned short* wb2  = (unsigned short*)(wsp + 40935424);  // 303104
  unsigned short* wom1 = (unsigned short*)(wsp + 41238528);  // 75776
  unsigned short* wom2 = (unsigned short*)(wsp + 41314304);  // 75776
  float* bias1 = (float*)(wsp + 41390080);
  float* bias2 = (float*)(wsp + 41390208);

  xcvt3<<<dim3(256, 4), 256, 0, stream>>>(x, xbf);
  prep5<<<(128 * KT2 + 255) / 256, 256, 0, stream>>>(
      w1, w2, ow1, mw1, ob1, mb1, ow2, mw2, ob2, mb2,
      bn1g, bn1b, bn1m, bn1v, wb1, wb2, wom1, wom2, bias1, bias2);

  dim3 grid(2048);
  dim3 blk(128);
  // layer 1
  gemm8<0, true><<<grid, blk, 0, stream>>>(xbf, wom1, nullptr, nullptr, bias1,
      nullptr, nullptr, nullptr, nullptr, offb, nullptr, mskb);
  gemm8<1, true><<<grid, blk, 0, stream>>>(xbf, wb1, offb, mskb, alpha,
      nullptr, nullptr, nullptr, nullptr, nullptr, r2bf, nullptr);
  // layer 2
  gemm8<0, false><<<grid, blk, 0, stream>>>(r2bf, wom2, nullptr, nullptr, bias2,
      nullptr, nullptr, nullptr, nullptr, offb, nullptr, mskb);
  gemm8<2, false><<<grid, blk, 0, stream>>>(r2bf, wb2, offb, mskb, bn2g,
      bn2b, bn2m, bn2v, x, out, nullptr, nullptr);
}

// Round 9
// 392.342 us; speedup vs baseline: 1.4974x; 1.4974x over previous
//
#include <hip/hip_runtime.h>
#include <hip/hip_bf16.h>
#include <math.h>

#define DEV_INLINE __device__ __forceinline__

typedef __attribute__((ext_vector_type(8))) short short8;
typedef __attribute__((ext_vector_type(8))) unsigned short ushort8v;
typedef __attribute__((ext_vector_type(4))) float f32x4;

constexpr int H = 128, W = 128, C = 128, B = 4;
constexpr int HWc = H * W;        // 16384
constexpr int KK = 9;
constexpr int KT2 = 1184;         // 37 chunks * 32

DEV_INLINE unsigned short f2bf(float f) {
  union { float f; unsigned u; } v; v.f = f;
  unsigned r = v.u + 0x7FFFu + ((v.u >> 16) & 1u);   // RNE
  return (unsigned short)(r >> 16);
}
DEV_INLINE float ubits(unsigned u) {
  union { unsigned u; float f; } v; v.u = u; return v.f;
}
DEV_INLINE float bfu(unsigned short u) { return ubits(((unsigned)u) << 16); }
DEV_INLINE unsigned pack2bf(float a, float b) {
  float2 t; t.x = a; t.y = b;
  __hip_bfloat162 h = __float22bfloat162_rn(t);
  union { __hip_bfloat162 h; unsigned u; } c; c.h = h;
  return c.u;
}

// ---------------- deform conv, K-split x2 ----------------
// Block = 128 thr (2 waves) on 32 positions; wave wv owns channel-groups
// {2wv, 2wv+1} (disjoint gathers AND disjoint weight chunks -> total traffic
// equals the unsplit kernel, wave count doubled). launch_bounds(128,2):
// register cap 256 -> NO spill (R8's (128,4) cap of 128 caused ~1 GB scratch).
// fp32 partials: wave1 -> LDS (overlays bilinear table), wave0 adds + epilogue.
// MODE 1: PReLU -> NHWC bf16. MODE 2: BN2 + NCHW fp32 residual -> fp32.
template<int MODE, bool BN>
__global__ __launch_bounds__(128, 2)
void dgemm(const unsigned short* __restrict__ src,     // NHWC bf16
           const unsigned short* __restrict__ wS,      // [37][8][64][8]
           const float* __restrict__ offs,
           const float* __restrict__ msk,
           const float* __restrict__ pA, const float* __restrict__ pB,
           const float* __restrict__ pM, const float* __restrict__ pV,
           const float* __restrict__ resid,
           float* __restrict__ outf,
           unsigned short* __restrict__ outh)
{
  __shared__ __attribute__((aligned(16))) char smem[16384];
  ushort2* sId = (ushort2*)smem;                       // [288], 1152 B
  float4*  sWt = (float4*)(smem + 1152);               // [288], 4608 B
  float*   red = (float*)smem;                         // overlays (16 KB)

  const int tid  = threadIdx.x;
  const int lane = tid & 63;
  const int m16  = lane & 15;
  const int q    = lane >> 4;
  const int wv   = tid >> 6;

  const int raw  = blockIdx.x;                // 2048 blocks
  const int xcd  = raw & 7;
  const int slot = raw >> 3;                  // [0,256)
  const int b    = xcd >> 1;
  const int hy   = ((xcd & 1) << 6) | (slot >> 2);
  const int hx0  = (slot & 3) << 5;           // 32-wide segment
  const unsigned short* __restrict__ srcB = src + ((size_t)b << 14) * C;

  // ---- bilinear table: 9 taps x 32 positions ----
  for (int e = tid; e < KK * 32; e += 128) {
    const int tap = e >> 5;
    const int hx  = hx0 + (e & 31);
    const int ky  = tap / 3, kx = tap - 3 * (tap / 3);
    const size_t ob = ((size_t)(b * 18 + 2 * tap) * H + hy) * W + hx;
    const float oy = offs[ob];
    const float ox = offs[ob + (size_t)HWc];
    const float mv = msk[((size_t)(b * 9 + tap) * H + hy) * W + hx];
    const float py = (float)(hy - 1 + ky) + oy;
    const float px = (float)(hx - 1 + kx) + ox;
    const float fy = floorf(py), fx = floorf(px);
    const float ay = py - fy, ax = px - fx;
    const int y0 = (int)fy, x0 = (int)fx;
    const int y1 = y0 + 1, x1 = x0 + 1;
    const float wyt = (1.f - ay) * (((unsigned)y0 < (unsigned)H) ? 1.f : 0.f);
    const float wyb = ay * (((unsigned)y1 < (unsigned)H) ? 1.f : 0.f);
    const int y0c = min(max(y0, 0), H - 1), y1c = min(max(y1, 0), H - 1);
    const int bx  = min(max(x0, 0), W - 2);
    float wA = 0.f, wB = 0.f;
    if (x0 == bx)          { wA = 1.f - ax; wB = ax; }
    else if (x1 == bx)     { wA = ax; }
    else if (x0 == bx + 1) { wB = 1.f - ax; }
    sId[e] = make_ushort2((unsigned short)(y0c * W + bx),
                          (unsigned short)(y1c * W + bx));
    sWt[e] = make_float4(mv * wyt * wA, mv * wyt * wB,
                         mv * wyb * wA, mv * wyb * wB);
  }
  __syncthreads();

  f32x4 acc[2][8];
  #pragma unroll
  for (int g = 0; g < 2; ++g)
    #pragma unroll
    for (int i = 0; i < 8; ++i) acc[g][i] = (f32x4){0.f, 0.f, 0.f, 0.f};

  const int choff = q << 3;

  for (int tap = 0; tap < 9; ++tap) {
    #pragma unroll
    for (int cgi = 0; cgi < 2; ++cgi) {
      const int cg = (wv << 1) + cgi;
      const int ch = (tap << 2) + cg;
      const int cbase = (cg << 5) + choff;
      // bfr for both position groups first (corner regs transient)
      union { unsigned u[4]; short8 s; } bfr[2];
      #pragma unroll
      for (int g = 0; g < 2; ++g) {
        const int e = (tap << 5) + (g << 4) + m16;
        const ushort2 id = sId[e];
        const float4  wt = sWt[e];
        const unsigned short* pT  = srcB + ((size_t)id.x * C + cbase);
        const unsigned short* pBt = srcB + ((size_t)id.y * C + cbase);
        const ushort8v TL = *(const ushort8v*)(pT);
        const ushort8v TR = *(const ushort8v*)(pT + C);
        const ushort8v BL = *(const ushort8v*)(pBt);
        const ushort8v BR = *(const ushort8v*)(pBt + C);
        float sv[8];
        #pragma unroll
        for (int j = 0; j < 8; ++j)
          sv[j] = wt.x * bfu(TL[j]) + wt.y * bfu(TR[j])
                + wt.z * bfu(BL[j]) + wt.w * bfu(BR[j]);
        #pragma unroll
        for (int t = 0; t < 4; ++t) bfr[g].u[t] = pack2bf(sv[2 * t], sv[2 * t + 1]);
      }
      // one afr load feeds two independent MFMAs
      const unsigned short* ap = wS + ((size_t)ch * 8 * 64 + lane) * 8;
      #pragma unroll
      for (int ot = 0; ot < 8; ++ot) {
        const short8 afr = *(const short8*)(ap + (size_t)ot * 512);
        acc[0][ot] = __builtin_amdgcn_mfma_f32_16x16x32_bf16(afr, bfr[0].s, acc[0][ot], 0, 0, 0);
        acc[1][ot] = __builtin_amdgcn_mfma_f32_16x16x32_bf16(afr, bfr[1].s, acc[1][ot], 0, 0, 0);
      }
    }
  }

  if constexpr (BN) {   // chunk 36 (BN-shift), wave 0 only
    if (wv == 0) {
      const unsigned short* ap = wS + ((size_t)36 * 8 * 64 + lane) * 8;
      #pragma unroll
      for (int g = 0; g < 2; ++g) {
        union { unsigned u[4]; short8 s; } bfr;
        float sv[8];
        #pragma unroll
        for (int j = 0; j < 8; ++j) {
          const int kj = (q << 3) + j;
          float s = 0.f;
          if (kj < KK) {
            const float4 wt = sWt[(kj << 5) + (g << 4) + m16];
            s = wt.x + wt.y + wt.z + wt.w;
          }
          sv[j] = s;
        }
        #pragma unroll
        for (int t = 0; t < 4; ++t) bfr.u[t] = pack2bf(sv[2 * t], sv[2 * t + 1]);
        #pragma unroll
        for (int ot = 0; ot < 8; ++ot) {
          const short8 afr = *(const short8*)(ap + (size_t)ot * 512);
          acc[g][ot] = __builtin_amdgcn_mfma_f32_16x16x32_bf16(afr, bfr.s, acc[g][ot], 0, 0, 0);
        }
      }
    }
  }

  // ---- K-split reduction (red overlays table; barrier-separated) ----
  __syncthreads();
  if (wv == 1) {
    #pragma unroll
    for (int g = 0; g < 2; ++g)
      #pragma unroll
      for (int ot = 0; ot < 8; ++ot)
        #pragma unroll
        for (int rg = 0; rg < 4; ++rg)
          red[(((g << 3) + ot) * 4 + rg) * 64 + lane] = acc[g][ot][rg];
  }
  __syncthreads();
  if (wv != 0) return;

  // ---- epilogue (wave 0): D col = m16 -> position, row = q*4+rg -> o ----
  #pragma unroll
  for (int g = 0; g < 2; ++g) {
    const int hx = hx0 + (g << 4) + m16;
    #pragma unroll
    for (int ot = 0; ot < 8; ++ot) {
      float vv4[4];
      #pragma unroll
      for (int rg = 0; rg < 4; ++rg)
        vv4[rg] = acc[g][ot][rg] + red[(((g << 3) + ot) * 4 + rg) * 64 + lane];
      if constexpr (MODE == 1) {
        const float a0 = pA[ot * 16 + (q << 2) + 0];
        const float a1 = pA[ot * 16 + (q << 2) + 1];
        const float a2 = pA[ot * 16 + (q << 2) + 2];
        const float a3 = pA[ot * 16 + (q << 2) + 3];
        uint2 st;
        st.x = pack2bf(vv4[0] > 0.f ? vv4[0] : a0 * vv4[0],
                       vv4[1] > 0.f ? vv4[1] : a1 * vv4[1]);
        st.y = pack2bf(vv4[2] > 0.f ? vv4[2] : a2 * vv4[2],
                       vv4[3] > 0.f ? vv4[3] : a3 * vv4[3]);
        const int n = (b << 14) + hy * W + hx;
        *(uint2*)(outh + (size_t)n * C + ot * 16 + (q << 2)) = st;
      } else {
        #pragma unroll
        for (int rg = 0; rg < 4; ++rg) {
          const int o = ot * 16 + (q << 2) + rg;
          const size_t oi = (((size_t)(b * C + o)) << 14) + hy * W + hx;
          const float s  = pA[o] * rsqrtf(pV[o] + 1e-5f);
          const float sh = pB[o] - pM[o] * s;
          outf[oi] = vv4[rg] * s + sh + resid[oi];
        }
      }
    }
  }
}

// ---------------- offset/mask conv: 1 wave, 16 positions ----------------
// Grid 4096 (16 waves/CU). Tiny acc (8 regs) -> deep pipelining headroom.
template<bool BN>
__global__ __launch_bounds__(64, 4)
void conv0(const unsigned short* __restrict__ src,     // NHWC bf16
           const unsigned short* __restrict__ wS,      // [37][2][64][8]
           const float* __restrict__ bias,
           float* __restrict__ outOff, float* __restrict__ outMsk)
{
  const int lane = threadIdx.x;
  const int m16  = lane & 15;
  const int q    = lane >> 4;

  const int raw  = blockIdx.x;                // 4096 blocks
  const int xcd  = raw & 7;
  const int slot = raw >> 3;                  // [0,512)
  const int b    = xcd >> 1;
  const int hy   = ((xcd & 1) << 6) | (slot >> 3);
  const int hx0  = (slot & 7) << 4;           // 16-wide segment
  const unsigned short* __restrict__ srcB = src + ((size_t)b << 14) * C;

  f32x4 acc[2];
  acc[0] = (f32x4){0.f, 0.f, 0.f, 0.f};
  acc[1] = (f32x4){0.f, 0.f, 0.f, 0.f};

  const int choff = q << 3;

  for (int tap = 0; tap < 9; ++tap) {
    const int ky = tap / 3, kx = tap - 3 * (tap / 3);
    const int iy = hy + ky - 1;
    const int ix = hx0 + m16 + kx - 1;
    const bool vok = ((unsigned)iy < (unsigned)H) && ((unsigned)ix < (unsigned)W);
    const int rb = vok ? (iy * W + ix) : 0;
    const unsigned short* rp = srcB + (size_t)rb * C + choff;
    // all 4 channel slices in flight first
    ushort8v v[4];
    #pragma unroll
    for (int cg = 0; cg < 4; ++cg)
      v[cg] = *(const ushort8v*)(rp + (cg << 5));
    #pragma unroll
    for (int cg = 0; cg < 4; ++cg) {
      union { unsigned u[4]; short8 s; } bfr;
      #pragma unroll
      for (int t = 0; t < 4; ++t) {
        const unsigned short lo = vok ? v[cg][2 * t]     : (unsigned short)0;
        const unsigned short hi = vok ? v[cg][2 * t + 1] : (unsigned short)0;
        bfr.u[t] = (unsigned)lo | ((unsigned)hi << 16);
      }
      const int ch = (tap << 2) + cg;
      const unsigned short* ap = wS + ((size_t)ch * 2 * 64 + lane) * 8;
      acc[0] = __builtin_amdgcn_mfma_f32_16x16x32_bf16(*(const short8*)(ap), bfr.s, acc[0], 0, 0, 0);
      acc[1] = __builtin_amdgcn_mfma_f32_16x16x32_bf16(*(const short8*)(ap + 512), bfr.s, acc[1], 0, 0, 0);
    }
  }
  if constexpr (BN) {   // chunk 36: validity column
    union { unsigned u[4]; short8 s; } bfr;
    float sv[8];
    #pragma unroll
    for (int j = 0; j < 8; ++j) {
      const int kj = (q << 3) + j;
      float s = 0.f;
      if (kj < KK) {
        const int ky = kj / 3, kx = kj - 3 * (kj / 3);
        const int iy = hy + ky - 1, ix = hx0 + m16 + kx - 1;
        s = (((unsigned)iy < (unsigned)H) && ((unsigned)ix < (unsigned)W)) ? 1.f : 0.f;
      }
      sv[j] = s;
    }
    #pragma unroll
    for (int t = 0; t < 4; ++t) bfr.u[t] = pack2bf(sv[2 * t], sv[2 * t + 1]);
    const unsigned short* ap = wS + ((size_t)36 * 2 * 64 + lane) * 8;
    acc[0] = __builtin_amdgcn_mfma_f32_16x16x32_bf16(*(const short8*)(ap), bfr.s, acc[0], 0, 0, 0);
    acc[1] = __builtin_amdgcn_mfma_f32_16x16x32_bf16(*(const short8*)(ap + 512), bfr.s, acc[1], 0, 0, 0);
  }

  const int hx = hx0 + m16;
  #pragma unroll
  for (int ot = 0; ot < 2; ++ot) {
    #pragma unroll
    for (int rg = 0; rg < 4; ++rg) {
      const int o = ot * 16 + (q << 2) + rg;
      const float vv = acc[ot][rg];
      if (o < 18) {
        outOff[((size_t)(b * 18 + o) * H + hy) * W + hx] = vv + bias[o];
      } else if (o < 27) {
        const float z = vv + bias[o];
        outMsk[((size_t)(b * 9 + (o - 18)) * H + hy) * W + hx] = 2.f / (1.f + expf(-z));
      }
    }
  }
}

// NCHW fp32 -> NHWC bf16, LDS-tiled (coalesced loads AND stores)
__global__ __launch_bounds__(256, 4)
void xcvt3(const float* __restrict__ x, unsigned short* __restrict__ xb)
{
  __shared__ unsigned tile[64 * 69];
  const int b   = blockIdx.y;
  const int p0  = blockIdx.x * 64;
  const int tid = threadIdx.x;
  const int pl  = tid & 63;
  const int cg  = tid >> 6;
  const float* __restrict__ xp = x + (((size_t)(b * C) + cg * 32) << 14) + p0 + pl;
  #pragma unroll
  for (int j = 0; j < 16; ++j) {
    const float a = xp[(size_t)(2 * j) << 14];
    const float c = xp[(size_t)(2 * j + 1) << 14];
    tile[pl * 69 + cg * 16 + j] = pack2bf(a, c);
  }
  __syncthreads();
  const int pl2 = tid >> 2;
  const int cq  = tid & 3;
  unsigned* dst = (unsigned*)(xb + (((size_t)(b << 14)) + p0 + pl2) * C + cq * 32);
  #pragma unroll
  for (int k = 0; k < 16; k += 4) {
    uint4 v;
    v.x = tile[pl2 * 69 + cq * 16 + k];
    v.y = tile[pl2 * 69 + cq * 16 + k + 1];
    v.z = tile[pl2 * 69 + cq * 16 + k + 2];
    v.w = tile[pl2 * 69 + cq * 16 + k + 3];
    *(uint4*)(dst + k) = v;
  }
}

// Swizzled weights, tap-major chunks: wS[((ch*NT+ot)*64+lane)*8+j] =
// w[o=ot*16+(lane&15)][c=(ch&3)*32+(lane>>4)*8+j][tap=ch>>2] (ch<36);
// ch==36: BN-shift col (kj=(lane>>4)*8+j < 9), layer-1 only.
__global__ void prep5(const float* __restrict__ w1, const float* __restrict__ w2,
                      const float* __restrict__ ow1, const float* __restrict__ mw1,
                      const float* __restrict__ ob1, const float* __restrict__ mb1,
                      const float* __restrict__ ow2, const float* __restrict__ mw2,
                      const float* __restrict__ ob2, const float* __restrict__ mb2,
                      const float* __restrict__ g, const float* __restrict__ bb,
                      const float* __restrict__ m, const float* __restrict__ v,
                      unsigned short* __restrict__ wb1, unsigned short* __restrict__ wb2,
                      unsigned short* __restrict__ wom1, unsigned short* __restrict__ wom2,
                      float* __restrict__ bias1, float* __restrict__ bias2)
{
  const int i = blockIdx.x * 256 + threadIdx.x;
  if (i < 128 * KT2) {              // deform, NT=8
    const int j = i & 7, lane = (i >> 3) & 63, ot = (i >> 9) & 7, ch = i >> 12;
    const int o = ot * 16 + (lane & 15);
    const int qj = ((lane >> 4) << 3) + j;
    unsigned short v1 = 0, v2 = 0;
    if (ch < 36) {
      const int tap = ch >> 2;
      const int c   = ((ch & 3) << 5) + qj;
      const float s = g[c] * rsqrtf(v[c] + 1e-5f);
      v1 = f2bf(w1[(size_t)(o * 128 + c) * 9 + tap] * s);
      v2 = f2bf(w2[(size_t)(o * 128 + c) * 9 + tap]);
    } else if (qj < KK) {
      float acc = 0.f;
      for (int c = 0; c < 128; ++c) {
        const float s  = g[c] * rsqrtf(v[c] + 1e-5f);
        const float sh = bb[c] - m[c] * s;
        acc += w1[(size_t)(o * 128 + c) * 9 + qj] * sh;
      }
      v1 = f2bf(acc);
    }
    wb1[i] = v1; wb2[i] = v2;
  }
  if (i < 32 * KT2) {               // offset/mask, NT=2
    const int j = i & 7, lane = (i >> 3) & 63, ot = (i >> 9) & 1, ch = i >> 10;
    const int o = ot * 16 + (lane & 15);
    const int qj = ((lane >> 4) << 3) + j;
    unsigned short v1 = 0, v2 = 0;
    if (ch < 36) {
      const int tap = ch >> 2;
      const int c   = ((ch & 3) << 5) + qj;
      const float s = g[c] * rsqrtf(v[c] + 1e-5f);
      if (o < 18) {
        v1 = f2bf(ow1[(size_t)(o * 128 + c) * 9 + tap] * s);
        v2 = f2bf(ow2[(size_t)(o * 128 + c) * 9 + tap]);
      } else if (o < 27) {
        v1 = f2bf(mw1[(size_t)((o - 18) * 128 + c) * 9 + tap] * s);
        v2 = f2bf(mw2[(size_t)((o - 18) * 128 + c) * 9 + tap]);
      }
    } else if (qj < KK && o < 27) {
      const float* wsrc = (o < 18) ? ow1 + (size_t)o * 1152
                                   : mw1 + (size_t)(o - 18) * 1152;
      float acc = 0.f;
      for (int c = 0; c < 128; ++c) {
        const float s  = g[c] * rsqrtf(v[c] + 1e-5f);
        const float sh = bb[c] - m[c] * s;
        acc += wsrc[(size_t)c * 9 + qj] * sh;
      }
      v1 = f2bf(acc);
    }
    wom1[i] = v1; wom2[i] = v2;
  }
  if (i < 32) {
    float b1 = 0.f, b2 = 0.f;
    if (i < 18)      { b1 = ob1[i];      b2 = ob2[i]; }
    else if (i < 27) { b1 = mb1[i - 18]; b2 = mb2[i - 18]; }
    bias1[i] = b1; bias2[i] = b2;
  }
}

extern "C" void kernel_launch(void* const* d_in, const int* in_sizes, int n_in,
                              void* d_out, int out_size, void* d_ws, size_t ws_size,
                              hipStream_t stream)
{
  const float* x     = (const float*)d_in[0];
  const float* bn1g  = (const float*)d_in[1];
  const float* bn1b  = (const float*)d_in[2];
  const float* bn1m  = (const float*)d_in[3];
  const float* bn1v  = (const float*)d_in[4];
  const float* ow1   = (const float*)d_in[5];
  const float* ob1   = (const float*)d_in[6];
  const float* mw1   = (const float*)d_in[7];
  const float* mb1   = (const float*)d_in[8];
  const float* w1    = (const float*)d_in[9];
  const float* alpha = (const float*)d_in[10];
  const float* ow2   = (const float*)d_in[11];
  const float* ob2   = (const float*)d_in[12];
  const float* mw2   = (const float*)d_in[13];
  const float* mb2   = (const float*)d_in[14];
  const float* w2    = (const float*)d_in[15];
  const float* bn2g  = (const float*)d_in[16];
  const float* bn2b  = (const float*)d_in[17];
  const float* bn2m  = (const float*)d_in[18];
  const float* bn2v  = (const float*)d_in[19];
  float* out = (float*)d_out;

  char* wsp = (char*)d_ws;
  unsigned short* xbf  = (unsigned short*)(wsp);             // NHWC bf16
  unsigned short* r2bf = (unsigned short*)(wsp + 16777216);  // NHWC bf16
  float* offb = (float*)(wsp + 33554432);                    // 4718592
  float* mskb = (float*)(wsp + 38273024);                    // 2359296
  unsigned short* wb1  = (unsigned short*)(wsp + 40632320);  // 303104
  unsigned short* wb2  = (unsigned short*)(wsp + 40935424);  // 303104
  unsigned short* wom1 = (unsigned short*)(wsp + 41238528);  // 75776
  unsigned short* wom2 = (unsigned short*)(wsp + 41314304);  // 75776
  float* bias1 = (float*)(wsp + 41390080);
  float* bias2 = (float*)(wsp + 41390208);

  xcvt3<<<dim3(256, 4), 256, 0, stream>>>(x, xbf);
  prep5<<<(128 * KT2 + 255) / 256, 256, 0, stream>>>(
      w1, w2, ow1, mw1, ob1, mb1, ow2, mw2, ob2, mb2,
      bn1g, bn1b, bn1m, bn1v, wb1, wb2, wom1, wom2, bias1, bias2);

  // layer 1
  conv0<true><<<4096, 64, 0, stream>>>(xbf, wom1, bias1, offb, mskb);
  dgemm<1, true><<<2048, 128, 0, stream>>>(xbf, wb1, offb, mskb, alpha,
      nullptr, nullptr, nullptr, nullptr, nullptr, r2bf);
  // layer 2
  conv0<false><<<4096, 64, 0, stream>>>(r2bf, wom2, bias2, offb, mskb);
  dgemm<2, false><<<2048, 128, 0, stream>>>(r2bf, wb2, offb, mskb, bn2g,
      bn2b, bn2m, bn2v, x, out, nullptr);
}

// Round 10
// 343.724 us; speedup vs baseline: 1.7092x; 1.1414x over previous
//
#include <hip/hip_runtime.h>
#include <hip/hip_bf16.h>
#include <math.h>

#define DEV_INLINE __device__ __forceinline__

typedef __attribute__((ext_vector_type(8))) short short8;
typedef __attribute__((ext_vector_type(8))) unsigned short ushort8v;
typedef __attribute__((ext_vector_type(4))) float f32x4;

constexpr int H = 128, W = 128, C = 128, B = 4;
constexpr int HWc = H * W;        // 16384
constexpr int KK = 9;
constexpr int KT2 = 1184;         // 37 chunks * 32

DEV_INLINE unsigned short f2bf(float f) {
  union { float f; unsigned u; } v; v.f = f;
  unsigned r = v.u + 0x7FFFu + ((v.u >> 16) & 1u);   // RNE
  return (unsigned short)(r >> 16);
}
DEV_INLINE float ubits(unsigned u) {
  union { unsigned u; float f; } v; v.u = u; return v.f;
}
DEV_INLINE float bfu(unsigned short u) { return ubits(((unsigned)u) << 16); }
DEV_INLINE unsigned pack2bf(float a, float b) {
  float2 t; t.x = a; t.y = b;
  __hip_bfloat162 h = __float22bfloat162_rn(t);
  union { __hip_bfloat162 h; unsigned u; } c; c.h = h;
  return c.u;
}

// Unified fused implicit-GEMM conv over NHWC bf16 source.
// Block = 256 thr (4 waves) x 64 positions (one 64-px row segment); wave wv
// owns positions wv*16..+16, FULL K (no split, no reduction). Grid 1024 =
// 4 blocks/CU = 16 waves/CU. Per chunk the A-tile (NT KB) is staged ONCE per
// block into double-buffered LDS (regs -> ds_write, 1 barrier/chunk) so the
// per-CU A-traffic is per-BLOCK not per-wave (R7/R9's 303 KB/wave L2->L1
// stream was the plateau). Waves read A via ds_read_b128 (2-way bank = free).
// Chunk ch<36: tap=ch>>2, cg=ch&3, k=q*8+j -> channel cg*32+q*8+j at tap.
// Chunk 36 (BN=true): B col = bilinear-weight sum (deform) / validity (plain);
// A rows = folded BN1-shift columns.
// MODE 0: plain conv O=32 -> fp32 offsets+mask. MODE 1: deform O=128, PReLU
// -> NHWC bf16. MODE 2: deform O=128, BN2 + NCHW fp32 residual -> fp32.
template<int MODE, bool BN>
__global__ __launch_bounds__(256, 4)
void gemmK(const unsigned short* __restrict__ src,     // NHWC bf16
           const unsigned short* __restrict__ wS,      // [37][NT][64][8]
           const float* __restrict__ offs,
           const float* __restrict__ msk,
           const float* __restrict__ pA, const float* __restrict__ pB,
           const float* __restrict__ pM, const float* __restrict__ pV,
           const float* __restrict__ resid,
           float* __restrict__ outf,                   // MODE0 offs / MODE2 out
           unsigned short* __restrict__ outh,          // MODE1 NHWC bf16
           float* __restrict__ out1)                   // MODE0 mask
{
  constexpr int NT   = (MODE == 0) ? 2 : 8;
  constexpr int NCH  = BN ? 37 : 36;
  constexpr int CHEL = NT * 64 * 8;                    // ushort per chunk tile
  __shared__ ushort2 sId[(MODE != 0) ? KK * 64 : 1];
  __shared__ float4  sWt[(MODE != 0) ? KK * 64 : 1];
  __shared__ __attribute__((aligned(16))) unsigned short aBuf[2][CHEL];

  const int tid  = threadIdx.x;
  const int lane = tid & 63;
  const int m16  = lane & 15;
  const int q    = lane >> 4;
  const int wv   = tid >> 6;

  const int raw  = blockIdx.x;                // 1024 blocks
  const int xcd  = raw & 7;
  const int slot = raw >> 3;                  // [0,128)
  const int b    = xcd >> 1;
  const int hy   = ((xcd & 1) << 6) | (slot >> 1);
  const int hx0  = (slot & 1) << 6;           // 64-wide segment
  const unsigned short* __restrict__ srcB = src + ((size_t)b << 14) * C;

  // ---- bilinear table: 9 taps x 64 positions ----
  if constexpr (MODE != 0) {
    for (int e = tid; e < KK * 64; e += 256) {
      const int tap = e >> 6;
      const int hx  = hx0 + (e & 63);
      const int ky  = tap / 3, kx = tap - 3 * (tap / 3);
      const size_t ob = ((size_t)(b * 18 + 2 * tap) * H + hy) * W + hx;
      const float oy = offs[ob];
      const float ox = offs[ob + (size_t)HWc];
      const float mv = msk[((size_t)(b * 9 + tap) * H + hy) * W + hx];
      const float py = (float)(hy - 1 + ky) + oy;
      const float px = (float)(hx - 1 + kx) + ox;
      const float fy = floorf(py), fx = floorf(px);
      const float ay = py - fy, ax = px - fx;
      const int y0 = (int)fy, x0 = (int)fx;
      const int y1 = y0 + 1, x1 = x0 + 1;
      const float wyt = (1.f - ay) * (((unsigned)y0 < (unsigned)H) ? 1.f : 0.f);
      const float wyb = ay * (((unsigned)y1 < (unsigned)H) ? 1.f : 0.f);
      const int y0c = min(max(y0, 0), H - 1), y1c = min(max(y1, 0), H - 1);
      const int bx  = min(max(x0, 0), W - 2);
      float wA = 0.f, wB = 0.f;
      if (x0 == bx)          { wA = 1.f - ax; wB = ax; }
      else if (x1 == bx)     { wA = ax; }
      else if (x0 == bx + 1) { wB = 1.f - ax; }
      sId[e] = make_ushort2((unsigned short)(y0c * W + bx),
                            (unsigned short)(y1c * W + bx));
      sWt[e] = make_float4(mv * wyt * wA, mv * wyt * wB,
                           mv * wyb * wA, mv * wyb * wB);
    }
  }

  // ---- stage chunk 0 ----
  if constexpr (NT == 8) {
    const uint4 s0 = *(const uint4*)(wS + tid * 16);
    const uint4 s1 = *(const uint4*)(wS + tid * 16 + 8);
    *(uint4*)(&aBuf[0][tid * 16]) = s0;
    *(uint4*)(&aBuf[0][tid * 16 + 8]) = s1;
  } else {
    const uint2 s0 = *(const uint2*)(wS + tid * 4);
    *(uint2*)(&aBuf[0][tid * 4]) = s0;
  }
  __syncthreads();

  f32x4 acc[NT];
  #pragma unroll
  for (int i = 0; i < NT; ++i) acc[i] = (f32x4){0.f, 0.f, 0.f, 0.f};

  const int pos = (wv << 4) + m16;            // block-local position
  const int hx  = hx0 + pos;
  const int cbq = q << 3;

  for (int ch = 0; ch < NCH; ++ch) {
    // prefetch next chunk's A-tile into regs (global, block-shared stream)
    uint4 s0, s1; uint2 t0;
    const bool more = (ch + 1 < NCH);
    if (more) {
      if constexpr (NT == 8) {
        s0 = *(const uint4*)(wS + (size_t)(ch + 1) * CHEL + tid * 16);
        s1 = *(const uint4*)(wS + (size_t)(ch + 1) * CHEL + tid * 16 + 8);
      } else {
        t0 = *(const uint2*)(wS + (size_t)(ch + 1) * CHEL + tid * 4);
      }
    }
    // ---- B fragment ----
    union { unsigned u[4]; short8 s; } bfr;
    if (ch < 36) {
      const int tap = ch >> 2, cg = ch & 3;
      const int cbase = (cg << 5) + cbq;
      if constexpr (MODE != 0) {
        const int e = (tap << 6) + pos;
        const ushort2 id = sId[e];
        const float4  wt = sWt[e];
        const unsigned short* pT  = srcB + ((size_t)id.x * C + cbase);
        const unsigned short* pBt = srcB + ((size_t)id.y * C + cbase);
        const ushort8v TL = *(const ushort8v*)(pT);
        const ushort8v TR = *(const ushort8v*)(pT + C);
        const ushort8v BL = *(const ushort8v*)(pBt);
        const ushort8v BR = *(const ushort8v*)(pBt + C);
        float sv[8];
        #pragma unroll
        for (int j = 0; j < 8; ++j)
          sv[j] = wt.x * bfu(TL[j]) + wt.y * bfu(TR[j])
                + wt.z * bfu(BL[j]) + wt.w * bfu(BR[j]);
        #pragma unroll
        for (int t = 0; t < 4; ++t) bfr.u[t] = pack2bf(sv[2 * t], sv[2 * t + 1]);
      } else {
        const int ky = tap / 3, kx = tap - 3 * (tap / 3);
        const int iy = hy + ky - 1;
        const int ix = hx + kx - 1;
        const bool vok = ((unsigned)iy < (unsigned)H) && ((unsigned)ix < (unsigned)W);
        const int rb = vok ? (iy * W + ix) : 0;
        const ushort8v v = *(const ushort8v*)(srcB + ((size_t)rb * C + cbase));
        #pragma unroll
        for (int t = 0; t < 4; ++t) {
          const unsigned short lo = vok ? v[2 * t]     : (unsigned short)0;
          const unsigned short hi = vok ? v[2 * t + 1] : (unsigned short)0;
          bfr.u[t] = (unsigned)lo | ((unsigned)hi << 16);
        }
      }
    } else {
      // BN-shift chunk
      float sv[8];
      #pragma unroll
      for (int j = 0; j < 8; ++j) {
        const int kj = cbq + j;
        float s = 0.f;
        if (kj < KK) {
          if constexpr (MODE != 0) {
            const float4 wt = sWt[(kj << 6) + pos];
            s = wt.x + wt.y + wt.z + wt.w;
          } else {
            const int ky = kj / 3, kx = kj - 3 * (kj / 3);
            const int iy = hy + ky - 1, ix = hx + kx - 1;
            s = (((unsigned)iy < (unsigned)H) && ((unsigned)ix < (unsigned)W)) ? 1.f : 0.f;
          }
        }
        sv[j] = s;
      }
      #pragma unroll
      for (int t = 0; t < 4; ++t) bfr.u[t] = pack2bf(sv[2 * t], sv[2 * t + 1]);
    }
    // ---- MFMA over output tiles (A from LDS) ----
    const unsigned short* rb = &aBuf[ch & 1][0];
    #pragma unroll
    for (int ot = 0; ot < NT; ++ot) {
      const short8 afr = *(const short8*)(rb + (ot * 64 + lane) * 8);
      acc[ot] = __builtin_amdgcn_mfma_f32_16x16x32_bf16(afr, bfr.s, acc[ot], 0, 0, 0);
    }
    // ---- write staged regs to the other buffer, then barrier ----
    if (more) {
      unsigned short* wd = &aBuf[(ch + 1) & 1][0];
      if constexpr (NT == 8) {
        *(uint4*)(wd + tid * 16) = s0;
        *(uint4*)(wd + tid * 16 + 8) = s1;
      } else {
        *(uint2*)(wd + tid * 4) = t0;
      }
    }
    __syncthreads();
  }

  // ---- epilogue: D col = m16 -> position, row = q*4+rg -> o ----
  #pragma unroll
  for (int ot = 0; ot < NT; ++ot) {
    if constexpr (MODE == 1) {
      const float a0 = pA[ot * 16 + (q << 2) + 0];
      const float a1 = pA[ot * 16 + (q << 2) + 1];
      const float a2 = pA[ot * 16 + (q << 2) + 2];
      const float a3 = pA[ot * 16 + (q << 2) + 3];
      const float v0 = acc[ot][0], v1 = acc[ot][1];
      const float v2 = acc[ot][2], v3 = acc[ot][3];
      uint2 st;
      st.x = pack2bf(v0 > 0.f ? v0 : a0 * v0, v1 > 0.f ? v1 : a1 * v1);
      st.y = pack2bf(v2 > 0.f ? v2 : a2 * v2, v3 > 0.f ? v3 : a3 * v3);
      const int n = (b << 14) + hy * W + hx;
      *(uint2*)(outh + (size_t)n * C + ot * 16 + (q << 2)) = st;
    } else {
      #pragma unroll
      for (int rg = 0; rg < 4; ++rg) {
        const int o = ot * 16 + (q << 2) + rg;
        const float vv = acc[ot][rg];
        if constexpr (MODE == 0) {
          if (o < 18) {
            outf[((size_t)(b * 18 + o) * H + hy) * W + hx] = vv + pA[o];
          } else if (o < 27) {
            const float z = vv + pA[o];
            out1[((size_t)(b * 9 + (o - 18)) * H + hy) * W + hx] = 2.f / (1.f + expf(-z));
          }
        } else {
          const size_t oi = (((size_t)(b * C + o)) << 14) + hy * W + hx;
          const float s  = pA[o] * rsqrtf(pV[o] + 1e-5f);
          const float sh = pB[o] - pM[o] * s;
          outf[oi] = vv * s + sh + resid[oi];
        }
      }
    }
  }
}

// NCHW fp32 -> NHWC bf16, LDS-tiled (coalesced loads AND stores)
__global__ __launch_bounds__(256, 4)
void xcvt3(const float* __restrict__ x, unsigned short* __restrict__ xb)
{
  __shared__ unsigned tile[64 * 69];
  const int b   = blockIdx.y;
  const int p0  = blockIdx.x * 64;
  const int tid = threadIdx.x;
  const int pl  = tid & 63;
  const int cg  = tid >> 6;
  const float* __restrict__ xp = x + (((size_t)(b * C) + cg * 32) << 14) + p0 + pl;
  #pragma unroll
  for (int j = 0; j < 16; ++j) {
    const float a = xp[(size_t)(2 * j) << 14];
    const float c = xp[(size_t)(2 * j + 1) << 14];
    tile[pl * 69 + cg * 16 + j] = pack2bf(a, c);
  }
  __syncthreads();
  const int pl2 = tid >> 2;
  const int cq  = tid & 3;
  unsigned* dst = (unsigned*)(xb + (((size_t)(b << 14)) + p0 + pl2) * C + cq * 32);
  #pragma unroll
  for (int k = 0; k < 16; k += 4) {
    uint4 v;
    v.x = tile[pl2 * 69 + cq * 16 + k];
    v.y = tile[pl2 * 69 + cq * 16 + k + 1];
    v.z = tile[pl2 * 69 + cq * 16 + k + 2];
    v.w = tile[pl2 * 69 + cq * 16 + k + 3];
    *(uint4*)(dst + k) = v;
  }
}

// Swizzled weights, tap-major chunks: wS[((ch*NT+ot)*64+lane)*8+j] =
// w[o=ot*16+(lane&15)][c=(ch&3)*32+(lane>>4)*8+j][tap=ch>>2] (ch<36);
// ch==36: BN-shift col (kj=(lane>>4)*8+j < 9), layer-1 only.
__global__ void prep5(const float* __restrict__ w1, const float* __restrict__ w2,
                      const float* __restrict__ ow1, const float* __restrict__ mw1,
                      const float* __restrict__ ob1, const float* __restrict__ mb1,
                      const float* __restrict__ ow2, const float* __restrict__ mw2,
                      const float* __restrict__ ob2, const float* __restrict__ mb2,
                      const float* __restrict__ g, const float* __restrict__ bb,
                      const float* __restrict__ m, const float* __restrict__ v,
                      unsigned short* __restrict__ wb1, unsigned short* __restrict__ wb2,
                      unsigned short* __restrict__ wom1, unsigned short* __restrict__ wom2,
                      float* __restrict__ bias1, float* __restrict__ bias2)
{
  const int i = blockIdx.x * 256 + threadIdx.x;
  if (i < 128 * KT2) {              // deform, NT=8
    const int j = i & 7, lane = (i >> 3) & 63, ot = (i >> 9) & 7, ch = i >> 12;
    const int o = ot * 16 + (lane & 15);
    const int qj = ((lane >> 4) << 3) + j;
    unsigned short v1 = 0, v2 = 0;
    if (ch < 36) {
      const int tap = ch >> 2;
      const int c   = ((ch & 3) << 5) + qj;
      const float s = g[c] * rsqrtf(v[c] + 1e-5f);
      v1 = f2bf(w1[(size_t)(o * 128 + c) * 9 + tap] * s);
      v2 = f2bf(w2[(size_t)(o * 128 + c) * 9 + tap]);
    } else if (qj < KK) {
      float acc = 0.f;
      for (int c = 0; c < 128; ++c) {
        const float s  = g[c] * rsqrtf(v[c] + 1e-5f);
        const float sh = bb[c] - m[c] * s;
        acc += w1[(size_t)(o * 128 + c) * 9 + qj] * sh;
      }
      v1 = f2bf(acc);
    }
    wb1[i] = v1; wb2[i] = v2;
  }
  if (i < 32 * KT2) {               // offset/mask, NT=2
    const int j = i & 7, lane = (i >> 3) & 63, ot = (i >> 9) & 1, ch = i >> 10;
    const int o = ot * 16 + (lane & 15);
    const int qj = ((lane >> 4) << 3) + j;
    unsigned short v1 = 0, v2 = 0;
    if (ch < 36) {
      const int tap = ch >> 2;
      const int c   = ((ch & 3) << 5) + qj;
      const float s = g[c] * rsqrtf(v[c] + 1e-5f);
      if (o < 18) {
        v1 = f2bf(ow1[(size_t)(o * 128 + c) * 9 + tap] * s);
        v2 = f2bf(ow2[(size_t)(o * 128 + c) * 9 + tap]);
      } else if (o < 27) {
        v1 = f2bf(mw1[(size_t)((o - 18) * 128 + c) * 9 + tap] * s);
        v2 = f2bf(mw2[(size_t)((o - 18) * 128 + c) * 9 + tap]);
      }
    } else if (qj < KK && o < 27) {
      const float* wsrc = (o < 18) ? ow1 + (size_t)o * 1152
                                   : mw1 + (size_t)(o - 18) * 1152;
      float acc = 0.f;
      for (int c = 0; c < 128; ++c) {
        const float s  = g[c] * rsqrtf(v[c] + 1e-5f);
        const float sh = bb[c] - m[c] * s;
        acc += wsrc[(size_t)c * 9 + qj] * sh;
      }
      v1 = f2bf(acc);
    }
    wom1[i] = v1; wom2[i] = v2;
  }
  if (i < 32) {
    float b1 = 0.f, b2 = 0.f;
    if (i < 18)      { b1 = ob1[i];      b2 = ob2[i]; }
    else if (i < 27) { b1 = mb1[i - 18]; b2 = mb2[i - 18]; }
    bias1[i] = b1; bias2[i] = b2;
  }
}

extern "C" void kernel_launch(void* const* d_in, const int* in_sizes, int n_in,
                              void* d_out, int out_size, void* d_ws, size_t ws_size,
                              hipStream_t stream)
{
  const float* x     = (const float*)d_in[0];
  const float* bn1g  = (const float*)d_in[1];
  const float* bn1b  = (const float*)d_in[2];
  const float* bn1m  = (const float*)d_in[3];
  const float* bn1v  = (const float*)d_in[4];
  const float* ow1   = (const float*)d_in[5];
  const float* ob1   = (const float*)d_in[6];
  const float* mw1   = (const float*)d_in[7];
  const float* mb1   = (const float*)d_in[8];
  const float* w1    = (const float*)d_in[9];
  const float* alpha = (const float*)d_in[10];
  const float* ow2   = (const float*)d_in[11];
  const float* ob2   = (const float*)d_in[12];
  const float* mw2   = (const float*)d_in[13];
  const float* mb2   = (const float*)d_in[14];
  const float* w2    = (const float*)d_in[15];
  const float* bn2g  = (const float*)d_in[16];
  const float* bn2b  = (const float*)d_in[17];
  const float* bn2m  = (const float*)d_in[18];
  const float* bn2v  = (const float*)d_in[19];
  float* out = (float*)d_out;

  char* wsp = (char*)d_ws;
  unsigned short* xbf  = (unsigned short*)(wsp);             // NHWC bf16
  unsigned short* r2bf = (unsigned short*)(wsp + 16777216);  // NHWC bf16
  float* offb = (float*)(wsp + 33554432);                    // 4718592
  float* mskb = (float*)(wsp + 38273024);                    // 2359296
  unsigned short* wb1  = (unsigned short*)(wsp + 40632320);  // 303104
  unsigned short* wb2  = (unsigned short*)(wsp + 40935424);  // 303104
  unsigned short* wom1 = (unsigned short*)(wsp + 41238528);  // 75776
  unsigned short* wom2 = (unsigned short*)(wsp + 41314304);  // 75776
  float* bias1 = (float*)(wsp + 41390080);
  float* bias2 = (float*)(wsp + 41390208);

  xcvt3<<<dim3(256, 4), 256, 0, stream>>>(x, xbf);
  prep5<<<(128 * KT2 + 255) / 256, 256, 0, stream>>>(
      w1, w2, ow1, mw1, ob1, mb1, ow2, mw2, ob2, mb2,
      bn1g, bn1b, bn1m, bn1v, wb1, wb2, wom1, wom2, bias1, bias2);

  // layer 1
  gemmK<0, true><<<1024, 256, 0, stream>>>(xbf, wom1, nullptr, nullptr, bias1,
      nullptr, nullptr, nullptr, nullptr, offb, nullptr, mskb);
  gemmK<1, true><<<1024, 256, 0, stream>>>(xbf, wb1, offb, mskb, alpha,
      nullptr, nullptr, nullptr, nullptr, nullptr, r2bf, nullptr);
  // layer 2
  gemmK<0, false><<<1024, 256, 0, stream>>>(r2bf, wom2, nullptr, nullptr, bias2,
      nullptr, nullptr, nullptr, nullptr, offb, nullptr, mskb);
  gemmK<2, false><<<1024, 256, 0, stream>>>(r2bf, wb2, offb, mskb, bn2g,
      bn2b, bn2m, bn2v, x, out, nullptr, nullptr);
}

// Round 11
// 332.908 us; speedup vs baseline: 1.7647x; 1.0325x over previous
//
#include <hip/hip_runtime.h>
#include <hip/hip_bf16.h>
#include <hip/hip_fp16.h>
#include <math.h>

#define DEV_INLINE __device__ __forceinline__

typedef __attribute__((ext_vector_type(8))) short short8;
typedef __attribute__((ext_vector_type(8))) unsigned short ushort8v;
typedef __attribute__((ext_vector_type(4))) float f32x4;

constexpr int H = 128, W = 128, C = 128, B = 4;
constexpr int KK = 9;
constexpr int KT2 = 1184;         // 37 chunks * 32

DEV_INLINE unsigned short f2bf(float f) {
  union { float f; unsigned u; } v; v.f = f;
  unsigned r = v.u + 0x7FFFu + ((v.u >> 16) & 1u);   // RNE
  return (unsigned short)(r >> 16);
}
DEV_INLINE float ubits(unsigned u) {
  union { unsigned u; float f; } v; v.u = u; return v.f;
}
DEV_INLINE float bfu(unsigned short u) { return ubits(((unsigned)u) << 16); }
DEV_INLINE unsigned pack2bf(float a, float b) {
  float2 t; t.x = a; t.y = b;
  __hip_bfloat162 h = __float22bfloat162_rn(t);
  union { __hip_bfloat162 h; unsigned u; } c; c.h = h;
  return c.u;
}
DEV_INLINE unsigned f2h2(float a, float b) {
  __half2 h = __floats2half2_rn(a, b);
  union { __half2 h; unsigned u; } c; c.h = h;
  return c.u;
}
DEV_INLINE float2 h2f2(unsigned u) {
  union { unsigned u; __half2 h; } c; c.u = u;
  return __half22float2(c.h);
}

// Fully fused deform layer over NHWC bf16: per block (64 positions = one
// 64-px row segment, 4 waves x 16 pos, full K):
//   Phase 1: offset/mask conv (NT=2, wOM streamed from global, no LDS) ->
//            bias + 2*sigmoid -> sOff LDS (overlays aBuf0, barrier-separated).
//   Phase 2: per-lane bilinear table in REGISTERS (9 taps: packed row-pair id
//            + 4 fp16 weights = 27 VGPRs; K-loop fully unrolled so indexing
//            stays constant). No sId/sWt LDS, no per-chunk table reads.
//   Phase 3: deform GEMM, A-tile (8 KB/chunk) double-buffered in LDS, staged
//            conflict-free (thread t -> slots t and t+256; 16-B lane stride).
// Chunk ch<36: tap=ch>>2, cg=ch&3, k=q*8+j -> channel cg*32+q*8+j at tap.
// LAYER 1 (BN): +chunk 36 (A rows = BN1-shift cols; B = wt-sum / validity);
//   epilogue PReLU -> NHWC bf16. LAYER 2: 36 chunks; BN2 + NCHW residual.
template<int LAYER>
__global__ __launch_bounds__(256, 4)
void fusedL(const unsigned short* __restrict__ src,     // NHWC bf16
            const unsigned short* __restrict__ wOM,     // [37][2][64][8]
            const unsigned short* __restrict__ wS,      // [37][8][64][8]
            const float* __restrict__ bias,             // [32]
            const float* __restrict__ pA, const float* __restrict__ pB,
            const float* __restrict__ pM, const float* __restrict__ pV,
            const float* __restrict__ resid,
            unsigned short* __restrict__ outh,          // LAYER1 NHWC bf16
            float* __restrict__ outf)                   // LAYER2 NCHW fp32
{
  constexpr bool BN   = (LAYER == 1);
  constexpr int  NCH3 = BN ? 37 : 36;
  __shared__ __attribute__((aligned(16))) char smem[16384];
  float* sOff = (float*)smem;                            // [64][29] = 7424 B
  unsigned short* aBuf0 = (unsigned short*)smem;         // 8 KB (overlays sOff)
  unsigned short* aBuf1 = (unsigned short*)(smem + 8192);

  const int tid  = threadIdx.x;
  const int lane = tid & 63;
  const int m16  = lane & 15;
  const int q    = lane >> 4;
  const int wv   = tid >> 6;

  const int raw  = blockIdx.x;                // 1024 blocks
  const int xcd  = raw & 7;
  const int slot = raw >> 3;                  // [0,128)
  const int b    = xcd >> 1;
  const int hy   = ((xcd & 1) << 6) | (slot >> 1);
  const int hx0  = (slot & 1) << 6;           // 64-wide segment
  const unsigned short* __restrict__ srcB = src + ((size_t)b << 14) * C;

  const int pos = (wv << 4) + m16;            // block-local position
  const int hx  = hx0 + pos;
  const int cbq = q << 3;

  // ================= Phase 1: offset/mask conv =================
  f32x4 acc2[2];
  acc2[0] = (f32x4){0.f, 0.f, 0.f, 0.f};
  acc2[1] = (f32x4){0.f, 0.f, 0.f, 0.f};

  for (int ch = 0; ch < 36; ++ch) {
    const int tap = ch >> 2, cg = ch & 3;
    const int ky = tap / 3, kx = tap - 3 * (tap / 3);
    const int iy = hy + ky - 1;
    const int ix = hx + kx - 1;
    const bool vok = ((unsigned)iy < (unsigned)H) && ((unsigned)ix < (unsigned)W);
    const int rb = vok ? (iy * W + ix) : 0;
    const ushort8v v = *(const ushort8v*)(srcB + ((size_t)rb * C + (cg << 5) + cbq));
    union { unsigned u[4]; short8 s; } bfr;
    #pragma unroll
    for (int t = 0; t < 4; ++t) {
      const unsigned short lo = vok ? v[2 * t]     : (unsigned short)0;
      const unsigned short hi = vok ? v[2 * t + 1] : (unsigned short)0;
      bfr.u[t] = (unsigned)lo | ((unsigned)hi << 16);
    }
    const unsigned short* ap = wOM + ((size_t)ch * 128 + lane) * 8;
    acc2[0] = __builtin_amdgcn_mfma_f32_16x16x32_bf16(*(const short8*)(ap), bfr.s, acc2[0], 0, 0, 0);
    acc2[1] = __builtin_amdgcn_mfma_f32_16x16x32_bf16(*(const short8*)(ap + 512), bfr.s, acc2[1], 0, 0, 0);
  }
  if constexpr (BN) {   // validity column chunk
    union { unsigned u[4]; short8 s; } bfr;
    float sv[8];
    #pragma unroll
    for (int j = 0; j < 8; ++j) {
      const int kj = cbq + j;
      float s = 0.f;
      if (kj < KK) {
        const int ky = kj / 3, kx = kj - 3 * (kj / 3);
        const int iy = hy + ky - 1, ix = hx + kx - 1;
        s = (((unsigned)iy < (unsigned)H) && ((unsigned)ix < (unsigned)W)) ? 1.f : 0.f;
      }
      sv[j] = s;
    }
    #pragma unroll
    for (int t = 0; t < 4; ++t) bfr.u[t] = pack2bf(sv[2 * t], sv[2 * t + 1]);
    const unsigned short* ap = wOM + ((size_t)36 * 128 + lane) * 8;
    acc2[0] = __builtin_amdgcn_mfma_f32_16x16x32_bf16(*(const short8*)(ap), bfr.s, acc2[0], 0, 0, 0);
    acc2[1] = __builtin_amdgcn_mfma_f32_16x16x32_bf16(*(const short8*)(ap + 512), bfr.s, acc2[1], 0, 0, 0);
  }
  // epilogue -> sOff (D col = m16 -> pos, row = q*4+rg -> o)
  #pragma unroll
  for (int ot = 0; ot < 2; ++ot) {
    #pragma unroll
    for (int rg = 0; rg < 4; ++rg) {
      const int o = ot * 16 + (q << 2) + rg;
      if (o < 27) {
        float v = acc2[ot][rg] + bias[o];
        if (o >= 18) v = 2.f / (1.f + expf(-v));
        sOff[pos * 29 + o] = v;
      }
    }
  }
  __syncthreads();

  // ================= Phase 2: per-lane bilinear table (registers) ==========
  unsigned tId[9], tW01[9], tW23[9];
  {
    const float* myOff = sOff + pos * 29;
    #pragma unroll
    for (int tap = 0; tap < 9; ++tap) {
      const int ky = tap / 3, kx = tap - 3 * (tap / 3);
      const float oy = myOff[2 * tap];
      const float ox = myOff[2 * tap + 1];
      const float mv = myOff[18 + tap];
      const float py = (float)(hy - 1 + ky) + oy;
      const float px = (float)(hx - 1 + kx) + ox;
      const float fy = floorf(py), fx = floorf(px);
      const float ay = py - fy, ax = px - fx;
      const int y0 = (int)fy, x0 = (int)fx;
      const int y1 = y0 + 1, x1 = x0 + 1;
      const float wyt = (1.f - ay) * (((unsigned)y0 < (unsigned)H) ? 1.f : 0.f);
      const float wyb = ay * (((unsigned)y1 < (unsigned)H) ? 1.f : 0.f);
      const int y0c = min(max(y0, 0), H - 1), y1c = min(max(y1, 0), H - 1);
      const int bx  = min(max(x0, 0), W - 2);
      float wA = 0.f, wB = 0.f;
      if (x0 == bx)          { wA = 1.f - ax; wB = ax; }
      else if (x1 == bx)     { wA = ax; }
      else if (x0 == bx + 1) { wB = 1.f - ax; }
      tId[tap]  = (unsigned)(y0c * W + bx) | ((unsigned)(y1c * W + bx) << 16);
      tW01[tap] = f2h2(mv * wyt * wA, mv * wyt * wB);
      tW23[tap] = f2h2(mv * wyb * wA, mv * wyb * wB);
    }
  }
  __syncthreads();   // sOff dead; aBuf0 may now be written

  // ================= Phase 3: deform GEMM =================
  // stage chunk 0 (thread t -> slots t and t+256; 16-B lane stride, no conflict)
  {
    const uint4 s0 = *(const uint4*)(wS + (size_t)tid * 8);
    const uint4 s1 = *(const uint4*)(wS + (size_t)(256 + tid) * 8);
    *(uint4*)(aBuf0 + (size_t)tid * 8) = s0;
    *(uint4*)(aBuf0 + (size_t)(256 + tid) * 8) = s1;
  }
  __syncthreads();

  f32x4 acc[8];
  #pragma unroll
  for (int i = 0; i < 8; ++i) acc[i] = (f32x4){0.f, 0.f, 0.f, 0.f};

  #pragma unroll
  for (int tap = 0; tap < 9; ++tap) {
    #pragma unroll
    for (int cg = 0; cg < 4; ++cg) {
      const int ch = (tap << 2) + cg;
      constexpr int LIM = NCH3;
      const bool more = (ch + 1 < LIM);
      uint4 s0, s1;
      if (more) {
        const size_t base = (size_t)(ch + 1) * 4096;
        s0 = *(const uint4*)(wS + base + (size_t)tid * 8);
        s1 = *(const uint4*)(wS + base + (size_t)(256 + tid) * 8);
      }
      // B fragment from register table
      const unsigned idp = tId[tap];
      const int rA = idp & 0xFFFF, rB = idp >> 16;
      const float2 w01 = h2f2(tW01[tap]);
      const float2 w23 = h2f2(tW23[tap]);
      const int cbase = (cg << 5) + cbq;
      const unsigned short* pT  = srcB + ((size_t)rA * C + cbase);
      const unsigned short* pBt = srcB + ((size_t)rB * C + cbase);
      const ushort8v TL = *(const ushort8v*)(pT);
      const ushort8v TR = *(const ushort8v*)(pT + C);
      const ushort8v BL = *(const ushort8v*)(pBt);
      const ushort8v BR = *(const ushort8v*)(pBt + C);
      union { unsigned u[4]; short8 s; } bfr;
      #pragma unroll
      for (int t = 0; t < 4; ++t) {
        const float sv0 = w01.x * bfu(TL[2 * t])     + w01.y * bfu(TR[2 * t])
                        + w23.x * bfu(BL[2 * t])     + w23.y * bfu(BR[2 * t]);
        const float sv1 = w01.x * bfu(TL[2 * t + 1]) + w01.y * bfu(TR[2 * t + 1])
                        + w23.x * bfu(BL[2 * t + 1]) + w23.y * bfu(BR[2 * t + 1]);
        bfr.u[t] = pack2bf(sv0, sv1);
      }
      const unsigned short* rbuf = (ch & 1) ? aBuf1 : aBuf0;
      #pragma unroll
      for (int ot = 0; ot < 8; ++ot) {
        const short8 afr = *(const short8*)(rbuf + ((size_t)(ot * 64 + lane)) * 8);
        acc[ot] = __builtin_amdgcn_mfma_f32_16x16x32_bf16(afr, bfr.s, acc[ot], 0, 0, 0);
      }
      if (more) {
        unsigned short* wd = ((ch + 1) & 1) ? aBuf1 : aBuf0;
        *(uint4*)(wd + (size_t)tid * 8) = s0;
        *(uint4*)(wd + (size_t)(256 + tid) * 8) = s1;
      }
      __syncthreads();
    }
  }

  if constexpr (BN) {   // chunk 36: BN-shift column (B = wt sums, from regs)
    float sv[8];
    if (q == 0) {
      #pragma unroll
      for (int j = 0; j < 8; ++j) {
        const float2 a = h2f2(tW01[j]);
        const float2 c = h2f2(tW23[j]);
        sv[j] = a.x + a.y + c.x + c.y;
      }
    } else if (q == 1) {
      const float2 a = h2f2(tW01[8]);
      const float2 c = h2f2(tW23[8]);
      sv[0] = a.x + a.y + c.x + c.y;
      #pragma unroll
      for (int j = 1; j < 8; ++j) sv[j] = 0.f;
    } else {
      #pragma unroll
      for (int j = 0; j < 8; ++j) sv[j] = 0.f;
    }
    union { unsigned u[4]; short8 s; } bfr;
    #pragma unroll
    for (int t = 0; t < 4; ++t) bfr.u[t] = pack2bf(sv[2 * t], sv[2 * t + 1]);
    #pragma unroll
    for (int ot = 0; ot < 8; ++ot) {
      const short8 afr = *(const short8*)(aBuf0 + ((size_t)(ot * 64 + lane)) * 8);
      acc[ot] = __builtin_amdgcn_mfma_f32_16x16x32_bf16(afr, bfr.s, acc[ot], 0, 0, 0);
    }
  }

  // ---- epilogue ----
  #pragma unroll
  for (int ot = 0; ot < 8; ++ot) {
    if constexpr (LAYER == 1) {
      const float a0 = pA[ot * 16 + (q << 2) + 0];
      const float a1 = pA[ot * 16 + (q << 2) + 1];
      const float a2 = pA[ot * 16 + (q << 2) + 2];
      const float a3 = pA[ot * 16 + (q << 2) + 3];
      const float v0 = acc[ot][0], v1 = acc[ot][1];
      const float v2 = acc[ot][2], v3 = acc[ot][3];
      uint2 st;
      st.x = pack2bf(v0 > 0.f ? v0 : a0 * v0, v1 > 0.f ? v1 : a1 * v1);
      st.y = pack2bf(v2 > 0.f ? v2 : a2 * v2, v3 > 0.f ? v3 : a3 * v3);
      const int n = (b << 14) + hy * W + hx;
      *(uint2*)(outh + (size_t)n * C + ot * 16 + (q << 2)) = st;
    } else {
      #pragma unroll
      for (int rg = 0; rg < 4; ++rg) {
        const int o = ot * 16 + (q << 2) + rg;
        const float vv = acc[ot][rg];
        const size_t oi = (((size_t)(b * C + o)) << 14) + hy * W + hx;
        const float s  = pA[o] * rsqrtf(pV[o] + 1e-5f);
        const float sh = pB[o] - pM[o] * s;
        outf[oi] = vv * s + sh + resid[oi];
      }
    }
  }
}

// NCHW fp32 -> NHWC bf16, LDS-tiled (coalesced loads AND stores)
__global__ __launch_bounds__(256, 4)
void xcvt3(const float* __restrict__ x, unsigned short* __restrict__ xb)
{
  __shared__ unsigned tile[64 * 69];
  const int b   = blockIdx.y;
  const int p0  = blockIdx.x * 64;
  const int tid = threadIdx.x;
  const int pl  = tid & 63;
  const int cg  = tid >> 6;
  const float* __restrict__ xp = x + (((size_t)(b * C) + cg * 32) << 14) + p0 + pl;
  #pragma unroll
  for (int j = 0; j < 16; ++j) {
    const float a = xp[(size_t)(2 * j) << 14];
    const float c = xp[(size_t)(2 * j + 1) << 14];
    tile[pl * 69 + cg * 16 + j] = pack2bf(a, c);
  }
  __syncthreads();
  const int pl2 = tid >> 2;
  const int cq  = tid & 3;
  unsigned* dst = (unsigned*)(xb + (((size_t)(b << 14)) + p0 + pl2) * C + cq * 32);
  #pragma unroll
  for (int k = 0; k < 16; k += 4) {
    uint4 v;
    v.x = tile[pl2 * 69 + cq * 16 + k];
    v.y = tile[pl2 * 69 + cq * 16 + k + 1];
    v.z = tile[pl2 * 69 + cq * 16 + k + 2];
    v.w = tile[pl2 * 69 + cq * 16 + k + 3];
    *(uint4*)(dst + k) = v;
  }
}

// Swizzled weights, tap-major chunks: wS[((ch*NT+ot)*64+lane)*8+j] =
// w[o=ot*16+(lane&15)][c=(ch&3)*32+(lane>>4)*8+j][tap=ch>>2] (ch<36);
// ch==36: BN-shift col (kj=(lane>>4)*8+j < 9), layer-1 only.
__global__ void prep5(const float* __restrict__ w1, const float* __restrict__ w2,
                      const float* __restrict__ ow1, const float* __restrict__ mw1,
                      const float* __restrict__ ob1, const float* __restrict__ mb1,
                      const float* __restrict__ ow2, const float* __restrict__ mw2,
                      const float* __restrict__ ob2, const float* __restrict__ mb2,
                      const float* __restrict__ g, const float* __restrict__ bb,
                      const float* __restrict__ m, const float* __restrict__ v,
                      unsigned short* __restrict__ wb1, unsigned short* __restrict__ wb2,
                      unsigned short* __restrict__ wom1, unsigned short* __restrict__ wom2,
                      float* __restrict__ bias1, float* __restrict__ bias2)
{
  const int i = blockIdx.x * 256 + threadIdx.x;
  if (i < 128 * KT2) {              // deform, NT=8
    const int j = i & 7, lane = (i >> 3) & 63, ot = (i >> 9) & 7, ch = i >> 12;
    const int o = ot * 16 + (lane & 15);
    const int qj = ((lane >> 4) << 3) + j;
    unsigned short v1 = 0, v2 = 0;
    if (ch < 36) {
      const int tap = ch >> 2;
      const int c   = ((ch & 3) << 5) + qj;
      const float s = g[c] * rsqrtf(v[c] + 1e-5f);
      v1 = f2bf(w1[(size_t)(o * 128 + c) * 9 + tap] * s);
      v2 = f2bf(w2[(size_t)(o * 128 + c) * 9 + tap]);
    } else if (qj < KK) {
      float acc = 0.f;
      for (int c = 0; c < 128; ++c) {
        const float s  = g[c] * rsqrtf(v[c] + 1e-5f);
        const float sh = bb[c] - m[c] * s;
        acc += w1[(size_t)(o * 128 + c) * 9 + qj] * sh;
      }
      v1 = f2bf(acc);
    }
    wb1[i] = v1; wb2[i] = v2;
  }
  if (i < 32 * KT2) {               // offset/mask, NT=2
    const int j = i & 7, lane = (i >> 3) & 63, ot = (i >> 9) & 1, ch = i >> 10;
    const int o = ot * 16 + (lane & 15);
    const int qj = ((lane >> 4) << 3) + j;
    unsigned short v1 = 0, v2 = 0;
    if (ch < 36) {
      const int tap = ch >> 2;
      const int c   = ((ch & 3) << 5) + qj;
      const float s = g[c] * rsqrtf(v[c] + 1e-5f);
      if (o < 18) {
        v1 = f2bf(ow1[(size_t)(o * 128 + c) * 9 + tap] * s);
        v2 = f2bf(ow2[(size_t)(o * 128 + c) * 9 + tap]);
      } else if (o < 27) {
        v1 = f2bf(mw1[(size_t)((o - 18) * 128 + c) * 9 + tap] * s);
        v2 = f2bf(mw2[(size_t)((o - 18) * 128 + c) * 9 + tap]);
      }
    } else if (qj < KK && o < 27) {
      const float* wsrc = (o < 18) ? ow1 + (size_t)o * 1152
                                   : mw1 + (size_t)(o - 18) * 1152;
      float acc = 0.f;
      for (int c = 0; c < 128; ++c) {
        const float s  = g[c] * rsqrtf(v[c] + 1e-5f);
        const float sh = bb[c] - m[c] * s;
        acc += wsrc[(size_t)c * 9 + qj] * sh;
      }
      v1 = f2bf(acc);
    }
    wom1[i] = v1; wom2[i] = v2;
  }
  if (i < 32) {
    float b1 = 0.f, b2 = 0.f;
    if (i < 18)      { b1 = ob1[i];      b2 = ob2[i]; }
    else if (i < 27) { b1 = mb1[i - 18]; b2 = mb2[i - 18]; }
    bias1[i] = b1; bias2[i] = b2;
  }
}

extern "C" void kernel_launch(void* const* d_in, const int* in_sizes, int n_in,
                              void* d_out, int out_size, void* d_ws, size_t ws_size,
                              hipStream_t stream)
{
  const float* x     = (const float*)d_in[0];
  const float* bn1g  = (const float*)d_in[1];
  const float* bn1b  = (const float*)d_in[2];
  const float* bn1m  = (const float*)d_in[3];
  const float* bn1v  = (const float*)d_in[4];
  const float* ow1   = (const float*)d_in[5];
  const float* ob1   = (const float*)d_in[6];
  const float* mw1   = (const float*)d_in[7];
  const float* mb1   = (const float*)d_in[8];
  const float* w1    = (const float*)d_in[9];
  const float* alpha = (const float*)d_in[10];
  const float* ow2   = (const float*)d_in[11];
  const float* ob2   = (const float*)d_in[12];
  const float* mw2   = (const float*)d_in[13];
  const float* mb2   = (const float*)d_in[14];
  const float* w2    = (const float*)d_in[15];
  const float* bn2g  = (const float*)d_in[16];
  const float* bn2b  = (const float*)d_in[17];
  const float* bn2m  = (const float*)d_in[18];
  const float* bn2v  = (const float*)d_in[19];
  float* out = (float*)d_out;

  char* wsp = (char*)d_ws;
  unsigned short* xbf  = (unsigned short*)(wsp);             // NHWC bf16
  unsigned short* r2bf = (unsigned short*)(wsp + 16777216);  // NHWC bf16
  unsigned short* wb1  = (unsigned short*)(wsp + 40632320);  // 303104
  unsigned short* wb2  = (unsigned short*)(wsp + 40935424);  // 303104
  unsigned short* wom1 = (unsigned short*)(wsp + 41238528);  // 75776
  unsigned short* wom2 = (unsigned short*)(wsp + 41314304);  // 75776
  float* bias1 = (float*)(wsp + 41390080);
  float* bias2 = (float*)(wsp + 41390208);

  xcvt3<<<dim3(256, 4), 256, 0, stream>>>(x, xbf);
  prep5<<<(128 * KT2 + 255) / 256, 256, 0, stream>>>(
      w1, w2, ow1, mw1, ob1, mb1, ow2, mw2, ob2, mb2,
      bn1g, bn1b, bn1m, bn1v, wb1, wb2, wom1, wom2, bias1, bias2);

  fusedL<1><<<1024, 256, 0, stream>>>(xbf, wom1, wb1, bias1, alpha,
      nullptr, nullptr, nullptr, nullptr, r2bf, nullptr);
  fusedL<2><<<1024, 256, 0, stream>>>(r2bf, wom2, wb2, bias2, bn2g,
      bn2b, bn2m, bn2v, x, nullptr, out);
}